// Round 7
// baseline (119.778 us; speedup 1.0000x reference)
//
#include <hip/hip_runtime.h>

// Problem constants: T=1024, B=256, H=20
#define T_N 1024
#define B_N 256
#define H_N 20
#define NW  8            // waves per block
#define NDW (NW - 1)     // dot waves
#define SIH 1096         // I-history row stride in HALVES (conflict-free layout, see R5)

typedef _Float16 h8_t __attribute__((ext_vector_type(8)));

#if __has_builtin(__builtin_amdgcn_fdot2)
#define DOT8(acc, mv, iv)                                                           \
    acc = __builtin_amdgcn_fdot2(__builtin_shufflevector(mv, mv, 0, 1),             \
                                 __builtin_shufflevector(iv, iv, 0, 1), acc, false);\
    acc = __builtin_amdgcn_fdot2(__builtin_shufflevector(mv, mv, 2, 3),             \
                                 __builtin_shufflevector(iv, iv, 2, 3), acc, false);\
    acc = __builtin_amdgcn_fdot2(__builtin_shufflevector(mv, mv, 4, 5),             \
                                 __builtin_shufflevector(iv, iv, 4, 5), acc, false);\
    acc = __builtin_amdgcn_fdot2(__builtin_shufflevector(mv, mv, 6, 7),             \
                                 __builtin_shufflevector(iv, iv, 6, 7), acc, false);
#else
#define DOT8(acc, mv, iv)                                                           \
    _Pragma("unroll")                                                               \
    for (int _k = 0; _k < 8; ++_k) acc = fmaf((float)mv[_k], (float)iv[_k], acc);
#endif

__device__ __forceinline__ float rdlane_i(float v, int lane) {
    return __uint_as_float((unsigned)__builtin_amdgcn_readlane((int)__float_as_uint(v), lane));
}
__device__ __forceinline__ float fast_tanh(float x) {
    const float e = __expf(2.0f * x);
    return fmaf(-2.0f, __builtin_amdgcn_rcpf(e + 1.0f), 1.0f);
}
__device__ __forceinline__ float fast_sigmoid(float x) {
    return __builtin_amdgcn_rcpf(1.0f + __expf(-x));
}

// explicit literal-token repetition (tokens must be plain literals for ##)
#define REP64(F) \
    F(0) F(1) F(2) F(3) F(4) F(5) F(6) F(7) F(8) F(9) F(10) F(11) F(12) F(13) \
    F(14) F(15) F(16) F(17) F(18) F(19) F(20) F(21) F(22) F(23) F(24) F(25)   \
    F(26) F(27) F(28) F(29) F(30) F(31) F(32) F(33) F(34) F(35) F(36) F(37)   \
    F(38) F(39) F(40) F(41) F(42) F(43) F(44) F(45) F(46) F(47) F(48) F(49)   \
    F(50) F(51) F(52) F(53) F(54) F(55) F(56) F(57) F(58) F(59) F(60) F(61)   \
    F(62) F(63)

// ---------------------------------------------------------------------------
// R7: BATCHED BROADCAST. Evidence: serial chain costs ~100cy/step; issue
// explains ~28cy (R3/R5 marginal fit 2.2cy/op); the ~70cy residual is
// op-count-invariant and survived store-drain (R1), pinning (R2), readlane
// LATENCY distance (R4), setprio (R5). The untested mechanism: the per-step
// v_readlane CADENCE (VALU->SGPR write woven into the dependent chain every
// step). This round groups steps by 8: 8 back-to-back readlanes at group
// start, then 8 steps whose sums are patched with up to 7 group-local
// recent terms (meTds * gi_{p-d}); any per-occurrence readlane
// serialization is paid once per 8 steps. Math identical (sum order only).
// me_kernel split (R6) and PA/PB conflict-free merge kept.
// ---------------------------------------------------------------------------
__global__ __launch_bounds__(512, 1) void me_kernel(
    const float* __restrict__ t,
    const float* __restrict__ w1, const float* __restrict__ b1,
    const float* __restrict__ w2, const float* __restrict__ b2,
    const float* __restrict__ w3, const float* __restrict__ b3,
    const float* __restrict__ w4, const float* __restrict__ b4,
    float* __restrict__ me_f,        // [1024] fp32
    _Float16* __restrict__ me_h)     // [1024] fp16
{
    const int gid = blockIdx.x * 512 + threadIdx.x;   // 2 blocks x 512 = 1024
    const float x = t[gid];

    float h1[H_N], h2[H_N];
#pragma unroll
    for (int k = 0; k < H_N; ++k) h1[k] = fast_tanh(fmaf(x, w1[k], b1[k]));

#pragma unroll 4
    for (int k = 0; k < H_N; ++k) {
        float a = b2[k];
#pragma unroll
        for (int j = 0; j < H_N; ++j) a = fmaf(h1[j], w2[j * H_N + k], a);
        h2[k] = fast_tanh(a);
    }

    float a4 = b4[0];
#pragma unroll 4
    for (int k = 0; k < H_N; ++k) {
        float a = b3[k];
#pragma unroll
        for (int j = 0; j < H_N; ++j) a = fmaf(h2[j], w3[j * H_N + k], a);
        a4 = fmaf(fast_tanh(a), w4[k], a4);
    }

    const float meval = fast_sigmoid(a4);
    me_f[gid] = meval;
    me_h[gid] = (_Float16)meval;
}

__global__ __launch_bounds__(512, 1) void scan_kernel(
    const float* __restrict__ me_f,
    const _Float16* __restrict__ me_h,
    const float* __restrict__ t,
    const float* __restrict__ y,
    const float* __restrict__ beta_p,
    const float* __restrict__ gamma_p,
    float* __restrict__ out)     // [solution (T*B*3) | diff (T*B*3)]
{
    __shared__ __align__(16) float    sMeF[T_N];      // fp32 me
    __shared__ __align__(16) _Float16 sMeH[T_N];      // fp16 me (dot operand A)
    __shared__ __align__(16) _Float16 sIhR[8 * SIH];  // 8 shifted fp16 I-history rows
    __shared__ __align__(16) float    PA[2][64][4];   // dot partials, waves 1-4
    __shared__ __align__(16) float    PB[2][64][4];   // dot partials, waves 5-7 (+zero slot)

    const int b   = blockIdx.x;
    const int tid = threadIdx.x;
    const int wid = tid >> 6;
    const int L   = tid & 63;

    // per-lane dot-geometry constants (chunk-invariant)
    const int f    = (-L) & 7;            // misalignment of lane L's me window
    const int R8   = L + f;               // L rounded up to multiple of 8
    const int row  = L & 7;               // I-history row for this lane
    const int iofs = row * SIH + (f ? 0 : 8);

    // zero the row front-pads (slots representing I[<0])
    if (tid < 64) sIhR[(tid >> 3) * SIH + (tid & 7)] = (_Float16)0.0f;
    // zero the unused PB slot 3 for both parities
    if (tid < 128) PB[tid >> 6][tid & 63][3] = 0.0f;

    // ---- stage me from global (computed by me_kernel) ----
#pragma unroll
    for (int v = 0; v < 2; ++v) {
        const int mi = tid + v * 512;
        sMeF[mi] = me_f[mi];
        sMeH[mi] = me_h[mi];
    }

    // ---- scalars / state ----
    const float dt    = t[0] - t[1];
    const float beta  = beta_p[0];
    const float gma   = gamma_p[0];
    const float invdt = 1.0f / dt;
    const float dt2   = dt * dt;

    const float S0 = y[b * 3 + 0];
    const float I0 = y[b * 3 + 1];
    const float R0 = y[b * 3 + 2];
    const float TOT = S0 + I0 + R0;     // SIR total conserved

    // publish I[0] into all 8 rows
    if (tid < 8) sIhR[tid * SIH + 8 - tid] = (_Float16)I0;

    float* __restrict__ diff = out + (size_t)T_N * B_N * 3;
    if (tid < 3) diff[((size_t)(T_N - 1) * B_N + b) * 3 + tid] = 0.0f;

    __syncthreads();   // sMeF/sMeH/pads/I0/PB-slot3 visible

    // fixup me weights (chunk-invariant, UNSCALED — applied to raw P sums)
    float mf[7];
#pragma unroll
    for (int d = 1; d <= 7; ++d) mf[d - 1] = sMeF[T_N - 64 - L - d];

    const float dtb   = dt * beta;
    const float ndtb  = -dtb;
    const float c1    = fmaf(-dt, gma, 1.0f);     // 1 - dt*gamma
    const float meT1s = dt2 * sMeF[T_N - 1];      // dt^2 * me[T-1]
    const float meT2s = dt2 * sMeF[T_N - 2];
    const float meT3s = dt2 * sMeF[T_N - 3];
    const float meT4s = dt2 * sMeF[T_N - 4];
    const float meT5s = dt2 * sMeF[T_N - 5];
    const float meT6s = dt2 * sMeF[T_N - 6];
    const float meT7s = dt2 * sMeF[T_N - 7];

    float S = S0, I = I0, oS = S0, oI = I0;
    float acc_cur = 0.0f, acc_nxt = 0.0f;
    float carryS = S0, carryI = I0;
    float rd_0 = 0.0f, rd_1 = 0.0f, rd_2 = 0.0f, rd_3 = 0.0f;
    float rd_4 = 0.0f, rd_5 = 0.0f, rd_6 = 0.0f, rd_7 = 0.0f;
    float gi0 = 0.0f, gi1 = 0.0f, gi2 = 0.0f, gi3 = 0.0f;
    float gi4 = 0.0f, gi5 = 0.0f, gi6 = 0.0f;

    // register me-tables (dt^2-scaled): 128 NAMED scalars
#define TBLDECL(k) float rm_##k, rn_##k;
    REP64(TBLDECL)
#undef TBLDECL
    if (wid == 0) {
#define TBLINIT(k)                                                          \
        rm_##k = (((k) < L) ? sMeF[T_N - L + (k)] : 0.0f) * dt2;            \
        rn_##k = dt2 * sMeF[T_N - 64 - L + (k)];
        REP64(TBLINIT)
#undef TBLINIT
#define TBLPIN(k) asm volatile("" : "+v"(rm_##k), "+v"(rn_##k));
        REP64(TBLPIN)
#undef TBLPIN
        // wave0 priority: serial VALU wave vs 7 LDS-heavy dot waves (T5)
        __builtin_amdgcn_s_setprio(3);
    }

    // ---- batched-broadcast group machinery ----
    // Patches: step at group position P needs Sum_{d=1..P} meTds * gi_{P-d}
    // (gi_k = I produced at group position k; rd_P was read before any
    //  this-group folds, so exactly the d<=P recent terms are missing).
#define PATCH0(s_)
#define PATCH1(s_) s_ = fmaf(meT1s, gi0, s_);
#define PATCH2(s_) s_ = fmaf(meT1s, gi1, fmaf(meT2s, gi0, s_));
#define PATCH3(s_) s_ = fmaf(meT1s, gi2, fmaf(meT2s, gi1, fmaf(meT3s, gi0, s_)));
#define PATCH4(s_) s_ = fmaf(meT1s, gi3, fmaf(meT2s, gi2, fmaf(meT3s, gi1, \
                        fmaf(meT4s, gi0, s_))));
#define PATCH5(s_) s_ = fmaf(meT1s, gi4, fmaf(meT2s, gi3, fmaf(meT3s, gi2, \
                        fmaf(meT4s, gi1, fmaf(meT5s, gi0, s_)))));
#define PATCH6(s_) s_ = fmaf(meT1s, gi5, fmaf(meT2s, gi4, fmaf(meT3s, gi3, \
                        fmaf(meT4s, gi2, fmaf(meT5s, gi1, fmaf(meT6s, gi0, s_))))));
#define PATCH7(s_) s_ = fmaf(meT1s, gi6, fmaf(meT2s, gi5, fmaf(meT3s, gi4, \
                        fmaf(meT4s, gi3, fmaf(meT5s, gi2, fmaf(meT6s, gi1, \
                        fmaf(meT7s, gi0, s_)))))));

    // one serial step at group position P_ producing y_{64c+M_}
#define GSTEP(M_, P_)                                                   \
    {                                                                   \
        float sum = rd_##P_;                                            \
        PATCH##P_(sum)                                                  \
        const float a  = fmaf(dtb, S, c1);                              \
        const float bb = fmaf(ndtb, I, 1.0f);                           \
        S = fmaf(bb, S, sum);                                           \
        I = I * a;                                                      \
        gi##P_ = I;                                                     \
        const bool cap = (L == (M_));                                   \
        oS = cap ? S : oS;                                              \
        oI = cap ? I : oI;                                              \
        acc_cur = fmaf(rm_##M_, I, acc_cur);                            \
        acc_nxt = fmaf(rn_##M_, I, acc_nxt);                            \
    }
    // gi7 is never needed as a patch source; GSTEP(...,7) writing gi7 would
    // waste a register, so position 7 uses a dedicated macro without store.
#define GSTEP7(M_)                                                      \
    {                                                                   \
        float sum = rd_7;                                               \
        PATCH7(sum)                                                     \
        const float a  = fmaf(dtb, S, c1);                              \
        const float bb = fmaf(ndtb, I, 1.0f);                           \
        S = fmaf(bb, S, sum);                                           \
        I = I * a;                                                      \
        const bool cap = (L == (M_));                                   \
        oS = cap ? S : oS;                                              \
        oI = cap ? I : oI;                                              \
        acc_cur = fmaf(rm_##M_, I, acc_cur);                            \
        acc_nxt = fmaf(rn_##M_, I, acc_nxt);                            \
    }

#define GREAD(B_)                                                       \
    rd_0 = rdlane_i(acc_cur, (B_) + 0);                                 \
    rd_1 = rdlane_i(acc_cur, (B_) + 1);                                 \
    rd_2 = rdlane_i(acc_cur, (B_) + 2);                                 \
    rd_3 = rdlane_i(acc_cur, (B_) + 3);                                 \
    rd_4 = rdlane_i(acc_cur, (B_) + 4);                                 \
    rd_5 = rdlane_i(acc_cur, (B_) + 5);                                 \
    rd_6 = rdlane_i(acc_cur, (B_) + 6);                                 \
    rd_7 = rdlane_i(acc_cur, (B_) + 7);

#define GROUP(B_, M0,M1,M2,M3,M4,M5,M6,M7)                              \
    GREAD(B_)                                                           \
    GSTEP(M0,0) GSTEP(M1,1) GSTEP(M2,2) GSTEP(M3,3)                     \
    GSTEP(M4,4) GSTEP(M5,5) GSTEP(M6,6) GSTEP7(M7)

#define GROUPS_8_63                                                     \
    GROUP(8,  8,9,10,11,12,13,14,15)                                    \
    GROUP(16, 16,17,18,19,20,21,22,23)                                  \
    GROUP(24, 24,25,26,27,28,29,30,31)                                  \
    GROUP(32, 32,33,34,35,36,37,38,39)                                  \
    GROUP(40, 40,41,42,43,44,45,46,47)                                  \
    GROUP(48, 48,49,50,51,52,53,54,55)                                  \
    GROUP(56, 56,57,58,59,60,61,62,63)

    for (int c = 0; c < 16; ++c) {
        if (wid == 0) {
            if (c == 0) {
                // fold initial I0 (tau=0 term); lane0's rm_0 is the 0 pad
                acc_cur = rm_0 * I;
                acc_nxt = rn_0 * I;
                // first group: steps 1..7 (7 steps, reads lanes 1..7)
                rd_0 = rdlane_i(acc_cur, 1);
                rd_1 = rdlane_i(acc_cur, 2);
                rd_2 = rdlane_i(acc_cur, 3);
                rd_3 = rdlane_i(acc_cur, 4);
                rd_4 = rdlane_i(acc_cur, 5);
                rd_5 = rdlane_i(acc_cur, 6);
                rd_6 = rdlane_i(acc_cur, 7);
                GSTEP(1,0) GSTEP(2,1) GSTEP(3,2) GSTEP(4,3)
                GSTEP(5,4) GSTEP(6,5) GSTEP(7,6)
                GROUPS_8_63
            } else {
                // chunk-head merge: 2x consecutive-per-lane ds_read_b128
                const float4 pa = *(const float4*)&PA[c & 1][L][0];
                const float4 pb = *(const float4*)&PB[c & 1][L][0];
                const float ps = ((pa.x + pa.y) + (pa.z + pa.w)) +
                                 ((pb.x + pb.y) + (pb.z + pb.w));   // PB slot3 = 0
                acc_cur = fmaf(dt2, ps, acc_nxt);  // scale raw P sums
                acc_nxt = 0.0f;
                GROUP(0, 0,1,2,3,4,5,6,7)
                GROUPS_8_63
            }

            // ---- chunk epilogue (wave 0) ----
            const int j = 64 * c + L;
            const _Float16 hI = (_Float16)oI;
#pragma unroll
            for (int r = 0; r < 8; ++r) sIhR[r * SIH + 8 + (j - r)] = hI;

            const float oR = TOT - oS - oI;
            const size_t so = ((size_t)j * B_N + b) * 3;
            out[so + 0] = oS;
            out[so + 1] = oI;
            out[so + 2] = oR;

            float sm1 = __shfl_up(oS, 1);
            float im1 = __shfl_up(oI, 1);
            if (L == 0) { sm1 = carryS; im1 = carryI; }
            if (j > 0) {
                const float d0 = (oS - sm1) * invdt;
                const float d1 = (oI - im1) * invdt;
                const float d2 = -d0 - d1;
                const size_t dofs = ((size_t)(j - 1) * B_N + b) * 3;
                diff[dofs + 0] = d0;
                diff[dofs + 1] = d1;
                diff[dofs + 2] = d2;
            }
            carryS = rdlane_i(oS, 63);
            carryI = rdlane_i(oI, 63);
        } else if (c < 15) {
            // history dot for chunk c+1 over tau < 64c (R5 layout, unchanged)
            const int w    = wid - 1;
            const int G    = 8 * c;
            const int idx0 = (T_N - 64 * (c + 1)) - R8;
            float p0 = 0.0f, p1 = 0.0f;
            int s = w;
            for (; s + NDW < G; s += 2 * NDW) {
                const h8_t mv0 = *(const h8_t*)&sMeH[idx0 + 8 * s];
                const h8_t iv0 = *(const h8_t*)&sIhR[iofs + 8 * s];
                const h8_t mv1 = *(const h8_t*)&sMeH[idx0 + 8 * (s + NDW)];
                const h8_t iv1 = *(const h8_t*)&sIhR[iofs + 8 * (s + NDW)];
                DOT8(p0, mv0, iv0)
                DOT8(p1, mv1, iv1)
            }
            if (s < G) {
                const h8_t mv0 = *(const h8_t*)&sMeH[idx0 + 8 * s];
                const h8_t iv0 = *(const h8_t*)&sIhR[iofs + 8 * s];
                DOT8(p0, mv0, iv0)
            }
            float p = p0 + p1;
            if (w == 0) {
                // tail fixup: tau = 64c - d, d = 1..f (raw, scaled at merge)
#pragma unroll
                for (int d = 1; d <= 7; ++d) {
                    const float ih = (float)sIhR[8 + 64 * c - d];   // row 0
                    if (d <= f) p = fmaf(mf[d - 1], ih, p);
                }
            }
            if (w < 4) PA[(c + 1) & 1][L][w] = p;
            else       PB[(c + 1) & 1][L][w - 4] = p;
        }
        __syncthreads();
    }
#undef GSTEP
#undef GSTEP7
#undef GREAD
#undef GROUP
#undef GROUPS_8_63
}

// ---------------------------------------------------------------------------
// Launcher: me_kernel (2 blocks) then scan_kernel (256 blocks), same stream.
// d_ws layout: [0,4096) fp32 me; [4096,6144) fp16 me.
// ---------------------------------------------------------------------------
extern "C" void kernel_launch(void* const* d_in, const int* in_sizes, int n_in,
                              void* d_out, int out_size, void* d_ws, size_t ws_size,
                              hipStream_t stream) {
    const float* t     = (const float*)d_in[0];
    const float* y     = (const float*)d_in[1];
    const float* w1    = (const float*)d_in[2];
    const float* b1    = (const float*)d_in[3];
    const float* w2    = (const float*)d_in[4];
    const float* b2    = (const float*)d_in[5];
    const float* w3    = (const float*)d_in[6];
    const float* b3    = (const float*)d_in[7];
    const float* w4    = (const float*)d_in[8];
    const float* b4    = (const float*)d_in[9];
    const float* beta  = (const float*)d_in[10];
    const float* gamma = (const float*)d_in[11];

    float*    me_f = (float*)d_ws;
    _Float16* me_h = (_Float16*)((char*)d_ws + 4096);

    me_kernel<<<2, 512, 0, stream>>>(t, w1, b1, w2, b2, w3, b3, w4, b4, me_f, me_h);
    scan_kernel<<<B_N, 512, 0, stream>>>(me_f, me_h, t, y, beta, gamma, (float*)d_out);
}

// Round 9
// 116.987 us; speedup vs baseline: 1.0239x; 1.0239x over previous
//
#include <hip/hip_runtime.h>

// Problem constants: T=1024, B=256, H=20
#define T_N 1024
#define B_N 256
#define H_N 20
#define NW  8            // waves per block
#define NDW (NW - 1)     // dot waves
#define SIH 1096         // I-history row stride in HALVES (conflict-free layout, see R5)

typedef _Float16 h8_t __attribute__((ext_vector_type(8)));

#if __has_builtin(__builtin_amdgcn_fdot2)
#define DOT8(acc, mv, iv)                                                           \
    acc = __builtin_amdgcn_fdot2(__builtin_shufflevector(mv, mv, 0, 1),             \
                                 __builtin_shufflevector(iv, iv, 0, 1), acc, false);\
    acc = __builtin_amdgcn_fdot2(__builtin_shufflevector(mv, mv, 2, 3),             \
                                 __builtin_shufflevector(iv, iv, 2, 3), acc, false);\
    acc = __builtin_amdgcn_fdot2(__builtin_shufflevector(mv, mv, 4, 5),             \
                                 __builtin_shufflevector(iv, iv, 4, 5), acc, false);\
    acc = __builtin_amdgcn_fdot2(__builtin_shufflevector(mv, mv, 6, 7),             \
                                 __builtin_shufflevector(iv, iv, 6, 7), acc, false);
#else
#define DOT8(acc, mv, iv)                                                           \
    _Pragma("unroll")                                                               \
    for (int _k = 0; _k < 8; ++_k) acc = fmaf((float)mv[_k], (float)iv[_k], acc);
#endif

__device__ __forceinline__ float rdlane_i(float v, int lane) {
    return __uint_as_float((unsigned)__builtin_amdgcn_readlane((int)__float_as_uint(v), lane));
}
__device__ __forceinline__ float fast_tanh(float x) {
    const float e = __expf(2.0f * x);
    return fmaf(-2.0f, __builtin_amdgcn_rcpf(e + 1.0f), 1.0f);
}
__device__ __forceinline__ float fast_sigmoid(float x) {
    return __builtin_amdgcn_rcpf(1.0f + __expf(-x));
}

// vcc-free capture: oD[lane M_] <- wave-uniform value held in SGPR sv_.
// v_writelane_b32 takes a literal lane select and ignores exec; the value
// comes from readfirstlane (exact: S,I are wave-uniform on wave 0).
#define WRLANE(oD_, sv_, M_) \
    asm("v_writelane_b32 %0, %1, " #M_ : "+v"(oD_) : "s"(sv_));

// explicit literal-token repetition (tokens must be plain literals for ##)
#define REP64(F) \
    F(0) F(1) F(2) F(3) F(4) F(5) F(6) F(7) F(8) F(9) F(10) F(11) F(12) F(13) \
    F(14) F(15) F(16) F(17) F(18) F(19) F(20) F(21) F(22) F(23) F(24) F(25)   \
    F(26) F(27) F(28) F(29) F(30) F(31) F(32) F(33) F(34) F(35) F(36) F(37)   \
    F(38) F(39) F(40) F(41) F(42) F(43) F(44) F(45) F(46) F(47) F(48) F(49)   \
    F(50) F(51) F(52) F(53) F(54) F(55) F(56) F(57) F(58) F(59) F(60) F(61)   \
    F(62) F(63)

// ---------------------------------------------------------------------------
// R8b: vcc-free serial step (R8 retry; builtin_writelane doesn't exist on
// gfx950 toolchain -> inline-asm v_writelane_b32 with literal lane).
// Theory: cy/step ~= 50 + 3.2*ops across R3-R7; the ~50cy op-count-invariant
// stall survived every prior surgery. The untested per-step serializer:
// capture via v_cmp(writes VCC)+v_cndmask(reads VCC) -- vcc is ONE physical
// resource, so consecutive steps cannot be interleaved by the scheduler.
// Replace capture with readfirstlane+writelane: no vcc anywhere in the
// 64-step body, and capture moves off the VALU pipe (SALU/lane-op).
// Also: unified chunk body (c==0 expressed as pre=0 + phantom I0-fold).
// Base otherwise = R6 (me_kernel split, PA/PB conflict-free merge,
// setprio(3), distance-1 readlane broadcast, dt^2-folded algebra).
// ---------------------------------------------------------------------------
__global__ __launch_bounds__(512, 1) void me_kernel(
    const float* __restrict__ t,
    const float* __restrict__ w1, const float* __restrict__ b1,
    const float* __restrict__ w2, const float* __restrict__ b2,
    const float* __restrict__ w3, const float* __restrict__ b3,
    const float* __restrict__ w4, const float* __restrict__ b4,
    float* __restrict__ me_f,        // [1024] fp32
    _Float16* __restrict__ me_h)     // [1024] fp16
{
    const int gid = blockIdx.x * 512 + threadIdx.x;   // 2 blocks x 512 = 1024
    const float x = t[gid];

    float h1[H_N], h2[H_N];
#pragma unroll
    for (int k = 0; k < H_N; ++k) h1[k] = fast_tanh(fmaf(x, w1[k], b1[k]));

#pragma unroll 4
    for (int k = 0; k < H_N; ++k) {
        float a = b2[k];
#pragma unroll
        for (int j = 0; j < H_N; ++j) a = fmaf(h1[j], w2[j * H_N + k], a);
        h2[k] = fast_tanh(a);
    }

    float a4 = b4[0];
#pragma unroll 4
    for (int k = 0; k < H_N; ++k) {
        float a = b3[k];
#pragma unroll
        for (int j = 0; j < H_N; ++j) a = fmaf(h2[j], w3[j * H_N + k], a);
        a4 = fmaf(fast_tanh(a), w4[k], a4);
    }

    const float meval = fast_sigmoid(a4);
    me_f[gid] = meval;
    me_h[gid] = (_Float16)meval;
}

__global__ __launch_bounds__(512, 1) void scan_kernel(
    const float* __restrict__ me_f,
    const _Float16* __restrict__ me_h,
    const float* __restrict__ t,
    const float* __restrict__ y,
    const float* __restrict__ beta_p,
    const float* __restrict__ gamma_p,
    float* __restrict__ out)     // [solution (T*B*3) | diff (T*B*3)]
{
    __shared__ __align__(16) float    sMeF[T_N];      // fp32 me
    __shared__ __align__(16) _Float16 sMeH[T_N];      // fp16 me (dot operand A)
    __shared__ __align__(16) _Float16 sIhR[8 * SIH];  // 8 shifted fp16 I-history rows
    __shared__ __align__(16) float    PA[2][64][4];   // dot partials, waves 1-4
    __shared__ __align__(16) float    PB[2][64][4];   // dot partials, waves 5-7 (+zero slot)

    const int b   = blockIdx.x;
    const int tid = threadIdx.x;
    const int wid = tid >> 6;
    const int L   = tid & 63;

    // per-lane dot-geometry constants (chunk-invariant)
    const int f    = (-L) & 7;            // misalignment of lane L's me window
    const int R8   = L + f;               // L rounded up to multiple of 8
    const int row  = L & 7;               // I-history row for this lane
    const int iofs = row * SIH + (f ? 0 : 8);

    // zero the row front-pads (slots representing I[<0])
    if (tid < 64) sIhR[(tid >> 3) * SIH + (tid & 7)] = (_Float16)0.0f;
    // zero the unused PB slot 3 for both parities
    if (tid < 128) PB[tid >> 6][tid & 63][3] = 0.0f;

    // ---- stage me from global (computed by me_kernel) ----
#pragma unroll
    for (int v = 0; v < 2; ++v) {
        const int mi = tid + v * 512;
        sMeF[mi] = me_f[mi];
        sMeH[mi] = me_h[mi];
    }

    // ---- scalars / state ----
    const float dt    = t[0] - t[1];
    const float beta  = beta_p[0];
    const float gma   = gamma_p[0];
    const float invdt = 1.0f / dt;
    const float dt2   = dt * dt;

    const float S0 = y[b * 3 + 0];
    const float I0 = y[b * 3 + 1];
    const float R0 = y[b * 3 + 2];
    const float TOT = S0 + I0 + R0;     // SIR total conserved

    // publish I[0] into all 8 rows
    if (tid < 8) sIhR[tid * SIH + 8 - tid] = (_Float16)I0;

    float* __restrict__ diff = out + (size_t)T_N * B_N * 3;
    if (tid < 3) diff[((size_t)(T_N - 1) * B_N + b) * 3 + tid] = 0.0f;

    __syncthreads();   // sMeF/sMeH/pads/I0/PB-slot3 visible

    // fixup me weights (chunk-invariant, UNSCALED — applied to raw P sums)
    float mf[7];
#pragma unroll
    for (int d = 1; d <= 7; ++d) mf[d - 1] = sMeF[T_N - 64 - L - d];

    const float dtb   = dt * beta;
    const float ndtb  = -dtb;
    const float c1    = fmaf(-dt, gma, 1.0f);     // 1 - dt*gamma
    const float meT1s = dt2 * sMeF[T_N - 1];      // dt^2 * me[T-1]

    float S = S0, I = I0, oS = S0, oI = I0;
    float acc_cur = 0.0f, acc_nxt = 0.0f, pre = 0.0f;
    float carryS = S0, carryI = I0;

    // register me-tables (dt^2-scaled): 128 NAMED scalars
#define TBLDECL(k) float rm_##k, rn_##k;
    REP64(TBLDECL)
#undef TBLDECL
    if (wid == 0) {
#define TBLINIT(k)                                                          \
        rm_##k = (((k) < L) ? sMeF[T_N - L + (k)] : 0.0f) * dt2;            \
        rn_##k = dt2 * sMeF[T_N - 64 - L + (k)];
        REP64(TBLINIT)
#undef TBLINIT
#define TBLPIN(k) asm volatile("" : "+v"(rm_##k), "+v"(rn_##k));
        REP64(TBLPIN)
#undef TBLPIN
        // wave0 priority: serial VALU wave vs 7 LDS-heavy dot waves (T5)
        __builtin_amdgcn_s_setprio(3);
    }

    // serial step M_: entering (S,I) = y_{64c+M_-1}; produces y_{64c+M_}.
    // pre was read BEFORE step (M_-1)'s fold -> patch with meT1s*I.
    // Capture: readfirstlane (SALU) + v_writelane literal-lane — no vcc.
#define STEPB(M_, FIRST_)                                               \
    {                                                                   \
        const float sum = (FIRST_) ? pre : fmaf(meT1s, I, pre);         \
        float pnx = pre;                                                \
        if ((M_) < 63) pnx = rdlane_i(acc_cur, (M_) + 1);               \
        const float a  = fmaf(dtb, S, c1);                              \
        const float bb = fmaf(ndtb, I, 1.0f);                           \
        S = fmaf(bb, S, sum);                                           \
        I = I * a;                                                      \
        const int svS = __builtin_amdgcn_readfirstlane((int)__float_as_uint(S)); \
        const int svI = __builtin_amdgcn_readfirstlane((int)__float_as_uint(I)); \
        WRLANE(oS, svS, M_)                                             \
        WRLANE(oI, svI, M_)                                             \
        acc_cur = fmaf(rm_##M_, I, acc_cur);                            \
        acc_nxt = fmaf(rn_##M_, I, acc_nxt);                            \
        pre = pnx;                                                      \
    }
#define STEP_GE2(M_) if ((M_) >= 2) STEPB(M_, false)

    for (int c = 0; c < 16; ++c) {
        if (wid == 0) {
            if (c == 0) {
                // phantom fold of I0 (tau=0 term) with pre read BEFORE it:
                // pre = 0, acc = rm_0 * I0. Step 1's patch meT1s*I0 then
                // supplies the d=1 term — identical math to R6's init.
                pre = 0.0f;
                acc_cur = rm_0 * I;
                acc_nxt = rn_0 * I;
            } else {
                // chunk-head merge: 2x consecutive-per-lane ds_read_b128
                const float4 pa = *(const float4*)&PA[c & 1][L][0];
                const float4 pb = *(const float4*)&PB[c & 1][L][0];
                const float ps = ((pa.x + pa.y) + (pa.z + pa.w)) +
                                 ((pb.x + pb.y) + (pb.z + pb.w));   // PB slot3 = 0
                acc_cur = fmaf(dt2, ps, acc_nxt);  // scale raw P sums
                acc_nxt = 0.0f;
                pre = rdlane_i(acc_cur, 0);
                STEPB(0, true)
            }
            // shared body: steps 1..63 (single instantiation, both paths)
            STEPB(1, false)
            REP64(STEP_GE2)

            // ---- chunk epilogue (wave 0) ----
            const int j = 64 * c + L;
            const _Float16 hI = (_Float16)oI;
#pragma unroll
            for (int r = 0; r < 8; ++r) sIhR[r * SIH + 8 + (j - r)] = hI;

            const float oR = TOT - oS - oI;
            const size_t so = ((size_t)j * B_N + b) * 3;
            out[so + 0] = oS;
            out[so + 1] = oI;
            out[so + 2] = oR;

            float sm1 = __shfl_up(oS, 1);
            float im1 = __shfl_up(oI, 1);
            if (L == 0) { sm1 = carryS; im1 = carryI; }
            if (j > 0) {
                const float d0 = (oS - sm1) * invdt;
                const float d1 = (oI - im1) * invdt;
                const float d2 = -d0 - d1;
                const size_t dofs = ((size_t)(j - 1) * B_N + b) * 3;
                diff[dofs + 0] = d0;
                diff[dofs + 1] = d1;
                diff[dofs + 2] = d2;
            }
            carryS = rdlane_i(oS, 63);
            carryI = rdlane_i(oI, 63);
        } else if (c < 15) {
            // history dot for chunk c+1 over tau < 64c (R5 layout, unchanged)
            const int w    = wid - 1;
            const int G    = 8 * c;
            const int idx0 = (T_N - 64 * (c + 1)) - R8;
            float p0 = 0.0f, p1 = 0.0f;
            int s = w;
            for (; s + NDW < G; s += 2 * NDW) {
                const h8_t mv0 = *(const h8_t*)&sMeH[idx0 + 8 * s];
                const h8_t iv0 = *(const h8_t*)&sIhR[iofs + 8 * s];
                const h8_t mv1 = *(const h8_t*)&sMeH[idx0 + 8 * (s + NDW)];
                const h8_t iv1 = *(const h8_t*)&sIhR[iofs + 8 * (s + NDW)];
                DOT8(p0, mv0, iv0)
                DOT8(p1, mv1, iv1)
            }
            if (s < G) {
                const h8_t mv0 = *(const h8_t*)&sMeH[idx0 + 8 * s];
                const h8_t iv0 = *(const h8_t*)&sIhR[iofs + 8 * s];
                DOT8(p0, mv0, iv0)
            }
            float p = p0 + p1;
            if (w == 0) {
                // tail fixup: tau = 64c - d, d = 1..f (raw, scaled at merge)
#pragma unroll
                for (int d = 1; d <= 7; ++d) {
                    const float ih = (float)sIhR[8 + 64 * c - d];   // row 0
                    if (d <= f) p = fmaf(mf[d - 1], ih, p);
                }
            }
            if (w < 4) PA[(c + 1) & 1][L][w] = p;
            else       PB[(c + 1) & 1][L][w - 4] = p;
        }
        __syncthreads();
    }
#undef STEPB
#undef STEP_GE2
}

// ---------------------------------------------------------------------------
// Launcher: me_kernel (2 blocks) then scan_kernel (256 blocks), same stream.
// d_ws layout: [0,4096) fp32 me; [4096,6144) fp16 me.
// ---------------------------------------------------------------------------
extern "C" void kernel_launch(void* const* d_in, const int* in_sizes, int n_in,
                              void* d_out, int out_size, void* d_ws, size_t ws_size,
                              hipStream_t stream) {
    const float* t     = (const float*)d_in[0];
    const float* y     = (const float*)d_in[1];
    const float* w1    = (const float*)d_in[2];
    const float* b1    = (const float*)d_in[3];
    const float* w2    = (const float*)d_in[4];
    const float* b2    = (const float*)d_in[5];
    const float* w3    = (const float*)d_in[6];
    const float* b3    = (const float*)d_in[7];
    const float* w4    = (const float*)d_in[8];
    const float* b4    = (const float*)d_in[9];
    const float* beta  = (const float*)d_in[10];
    const float* gamma = (const float*)d_in[11];

    float*    me_f = (float*)d_ws;
    _Float16* me_h = (_Float16*)((char*)d_ws + 4096);

    me_kernel<<<2, 512, 0, stream>>>(t, w1, b1, w2, b2, w3, b3, w4, b4, me_f, me_h);
    scan_kernel<<<B_N, 512, 0, stream>>>(me_f, me_h, t, y, beta, gamma, (float*)d_out);
}